// Round 6
// baseline (480.727 us; speedup 1.0000x reference)
//
#include <hip/hip_runtime.h>
#include <hip/hip_bf16.h>

// Problem constants
#define BHALF 4096      // B = 8192/2
#define DDIM 128        // feature dim per matrix
#define KCAT 384        // 3*DDIM, packed row width
#define TEMP_INV 10.0f  // 1/TEMP
#define EXP2K 14.426950408889634f  // 10 * log2(e): exp(v*10) = exp2(v*EXP2K)

typedef __attribute__((ext_vector_type(8))) short short8;    // 8 bf16
typedef __attribute__((ext_vector_type(16))) float f32x16;   // 32x32 MFMA acc

// Async global->LDS, 16B per lane. LDS dest is wave-uniform base (HW adds
// lane*16). Global source is per-lane.
__device__ __forceinline__ void gload16(const ushort* g, ushort* l) {
  __builtin_amdgcn_global_load_lds(
      (const __attribute__((address_space(1))) unsigned int*)g,
      (__attribute__((address_space(3))) unsigned int*)l, 16, 0, 0);
}

// ---------------------------------------------------------------------------
// Fused normalize + diag: one wave per (matrix, row-pair i).
__global__ __launch_bounds__(256) void norm_diag_kernel(
    const float* __restrict__ x, const float* __restrict__ y,
    const float* __restrict__ z, ushort* __restrict__ nrm1,
    ushort* __restrict__ nrm2, float* __restrict__ dxyz) {
  int wave = threadIdx.x >> 6;
  int lane = threadIdx.x & 63;
  int gi = blockIdx.x * 4 + wave;  // 0 .. 3*4096-1
  int mat = gi >> 12;
  int i = gi & 4095;
  const float* src = (mat == 0 ? x : (mat == 1 ? y : z));
  float2 a = *(const float2*)(src + (size_t)i * DDIM + lane * 2);
  float2 b = *(const float2*)(src + (size_t)(i + BHALF) * DDIM + lane * 2);
  float s1 = a.x * a.x + a.y * a.y;
  float s2 = b.x * b.x + b.y * b.y;
  float d = a.x * b.x + a.y * b.y;
#pragma unroll
  for (int m = 1; m < 64; m <<= 1) {
    s1 += __shfl_xor(s1, m, 64);
    s2 += __shfl_xor(s2, m, 64);
    d += __shfl_xor(d, m, 64);
  }
  float r1 = 1.0f / fmaxf(sqrtf(s1), 1e-12f);
  float r2 = 1.0f / fmaxf(sqrtf(s2), 1e-12f);
  ushort* d1 = nrm1 + (size_t)i * KCAT + mat * DDIM + lane * 2;
  ushort* d2 = nrm2 + (size_t)i * KCAT + mat * DDIM + lane * 2;
  __hip_bfloat162 o1, o2;
  o1.x = __float2bfloat16(a.x * r1);
  o1.y = __float2bfloat16(a.y * r1);
  o2.x = __float2bfloat16(b.x * r2);
  o2.y = __float2bfloat16(b.y * r2);
  *(__hip_bfloat162*)d1 = o1;
  *(__hip_bfloat162*)d2 = o2;
  if (lane == 0) dxyz[mat * BHALF + i] = d * r1 * r2;
}

// ---------------------------------------------------------------------------
// Flush helpers. 32x32 C/D layout (m74/m101): col = lane&31,
// row = (reg&3) + 8*(reg>>2) + 4*(lane>>5), reg 0..15.

// Cheap direction only (sum over D-rows, one value per D-col). Used for the
// transposed g3: D[j][i], sum over j, atomic per i.
__device__ __forceinline__ void flush_cheap(f32x16 (&acc)[4][2],
                                            float* __restrict__ dst, int base,
                                            int lane) {
#pragma unroll
  for (int m = 0; m < 4; ++m) {
    float s = 0.0f;
#pragma unroll
    for (int n = 0; n < 2; ++n)
#pragma unroll
      for (int r = 0; r < 16; ++r) s += exp2f(acc[m][n][r] * EXP2K);
    s += __shfl_xor(s, 32, 64);
    if (lane < 32) atomicAdd(&dst[base + m * 32 + lane], s);
#pragma unroll
    for (int n = 0; n < 2; ++n)
#pragma unroll
      for (int r = 0; r < 16; ++r) acc[m][n][r] = 0.0f;
  }
}

// Full flush: D[i][j]; rs[i] += sum_j exp, cs[j] += sum_i exp.
__device__ __forceinline__ void flush_full(f32x16 (&acc)[4][2],
                                           float* __restrict__ rs,
                                           float* __restrict__ cs, int rbase,
                                           int cbase, int lane) {
#pragma unroll
  for (int m = 0; m < 4; ++m)
#pragma unroll
    for (int n = 0; n < 2; ++n)
#pragma unroll
      for (int r = 0; r < 16; ++r)
        acc[m][n][r] = exp2f(acc[m][n][r] * EXP2K);

  // col sums (cheap: lane-local over regs, + half swap)
#pragma unroll
  for (int n = 0; n < 2; ++n) {
    float c = 0.0f;
#pragma unroll
    for (int m = 0; m < 4; ++m)
#pragma unroll
      for (int r = 0; r < 16; ++r) c += acc[m][n][r];
    c += __shfl_xor(c, 32, 64);
    if (lane < 32) atomicAdd(&cs[cbase + n * 32 + lane], c);
  }

  // row sums (expensive: reduce 16 regs across 32-lane half)
  int h = lane >> 5;
#pragma unroll
  for (int m = 0; m < 4; ++m) {
    float rr[16];
#pragma unroll
    for (int r = 0; r < 16; ++r) rr[r] = acc[m][0][r] + acc[m][1][r];
#pragma unroll
    for (int s = 1; s <= 16; s <<= 1)
#pragma unroll
      for (int r = 0; r < 16; ++r) rr[r] += __shfl_xor(rr[r], s, 64);
    if ((lane & 31) == 0) {
#pragma unroll
      for (int r = 0; r < 16; ++r)
        atomicAdd(&rs[rbase + m * 32 + (r & 3) + 8 * (r >> 2) + 4 * h], rr[r]);
    }
#pragma unroll
    for (int n = 0; n < 2; ++n)
#pragma unroll
      for (int r = 0; r < 16; ++r) acc[m][n][r] = 0.0f;
  }
}

// ---------------------------------------------------------------------------
// Fused 4-gram kernel: one block per (bi,bj) 256x256 tile pair, 8 waves
// (2 row x 4 col), 32x32x16 bf16 MFMA, BK=64, 12 K-steps:
//   t 0-5 : g3^T = nrm2[bj]·nrm1[bi]^T (K=384, operand-swapped so the only
//           needed sum is the cheap direction)
//   t 6-7 : g0 = x1·y1^T   t 8-9: g1 = x1·z1^T   t 10-11: g2 = y1·z1^T
// Double-buffered global_load_lds staging, counted vmcnt(8).
// LDS rows are 128B: involution swizzle chunk ^= (row&7) on source + read.
// NOTE: no occupancy arg in __launch_bounds__ — R5's (512,2) capped the
// allocator at 128 VGPR (min-BLOCKS interpretation) and spilled the 128-reg
// accumulator to scratch (1.18 GB WRITE_SIZE, 486 us).
// sums layout (4096 floats each): [rs0, cs0, rs1, cs1, rs2, cs2, rs3]
__global__ __launch_bounds__(512) void gram_fused_kernel(
    const ushort* __restrict__ nrm1, const ushort* __restrict__ nrm2,
    float* __restrict__ sums) {
  __shared__ ushort As[2 * 256 * 64];  // [buf][row 256][64 ushort = 128B]
  __shared__ ushort Bs[2 * 256 * 64];

  int tid = threadIdx.x;
  int lane = tid & 63;
  int wave = tid >> 6;   // 0..7
  int wr = wave >> 2;    // 0..1: rows wr*128
  int wc = wave & 3;     // 0..3: cols wc*64

  int rowbase = blockIdx.x * 256;
  int colbase = blockIdx.y * 256;

  // Staging: per wave 4 A-loads + 4 B-loads per step; load ld covers rows
  // [wave*32 + ld*8, +8). Lane l -> row +(l>>3), 16B slot (l&7); source
  // chunk pre-swizzled by (row&7) = ((l>>3)&7).
  int srow = lane >> 3;
  int schunk = ((lane & 7) ^ (srow & 7)) << 3;  // ushort offset
  const ushort* gA =
      nrm1 + (size_t)(rowbase + wave * 32 + srow) * KCAT + schunk;
  const ushort* gB1 =
      nrm1 + (size_t)(colbase + wave * 32 + srow) * KCAT + schunk;
  const ushort* gB2 =
      nrm2 + (size_t)(colbase + wave * 32 + srow) * KCAT + schunk;
  int ldsStageBase = wave * 2048;  // ushort index of wave's first row

  // Fragment reads: lane l -> row (l&31), k-chunk (h*2 + (l>>5)),
  // slot = chunk ^ (row&7).
  int frow = lane & 31;
  int fc = lane >> 5;
  int r7 = frow & 7;
  int aRow = (wr * 128 + frow) * 64;  // + m*2048 + swizzled slot
  int bRow = (wc * 64 + frow) * 64;   // + n*2048

  f32x16 acc[4][2] = {};

#define SCHED(t, ao, bp)                                   \
  do {                                                     \
    if ((t) < 6) { ao = (t) * 64; bp = gB2 + (t) * 64; }   \
    else if ((t) < 8) { ao = ((t)-6) * 64; bp = gB1 + 128 + ((t)-6) * 64; } \
    else if ((t) < 10) { ao = ((t)-8) * 64; bp = gB1 + 256 + ((t)-8) * 64; } \
    else { ao = ((t)-10) * 64 + 128; bp = gB1 + 256 + ((t)-10) * 64; }      \
  } while (0)

#define STAGE(b, ao, bp)                                              \
  do {                                                                \
    _Pragma("unroll") for (int ld = 0; ld < 4; ++ld) {                \
      gload16(gA + (ao) + (size_t)ld * 8 * KCAT,                      \
              &As[(b)*16384 + ldsStageBase + ld * 512]);              \
      gload16((bp) + (size_t)ld * 8 * KCAT,                           \
              &Bs[(b)*16384 + ldsStageBase + ld * 512]);              \
    }                                                                 \
  } while (0)

  {
    int ao; const ushort* bp;
    SCHED(0, ao, bp);
    STAGE(0, ao, bp);
  }

  int buf = 0;
  for (int gt = 0; gt < 12; ++gt) {
    if (gt < 11) {
      int ao; const ushort* bp;
      SCHED(gt + 1, ao, bp);
      STAGE(buf ^ 1, ao, bp);
      // wait only for this step's 8 loads; next step's 8 stay in flight
      asm volatile("s_waitcnt vmcnt(8)" ::: "memory");
    } else {
      asm volatile("s_waitcnt vmcnt(0)" ::: "memory");
    }
    __builtin_amdgcn_s_barrier();
    __builtin_amdgcn_sched_barrier(0);  // no LDS-read hoisting above barrier

    const ushort* A = &As[buf * 16384];
    const ushort* B = &Bs[buf * 16384];
    bool g3 = (gt < 6);
#pragma unroll
    for (int h = 0; h < 4; ++h) {
      int sl = (((h * 2 + fc) ^ r7) << 3);
      short8 af[4], bf[2];
#pragma unroll
      for (int m = 0; m < 4; ++m)
        af[m] = *(const short8*)&A[aRow + m * 2048 + sl];
#pragma unroll
      for (int n = 0; n < 2; ++n)
        bf[n] = *(const short8*)&B[bRow + n * 2048 + sl];
      if (g3) {
#pragma unroll
        for (int m = 0; m < 4; ++m)
#pragma unroll
          for (int n = 0; n < 2; ++n)
            acc[m][n] = __builtin_amdgcn_mfma_f32_32x32x16_bf16(
                bf[n], af[m], acc[m][n], 0, 0, 0);
      } else {
#pragma unroll
        for (int m = 0; m < 4; ++m)
#pragma unroll
          for (int n = 0; n < 2; ++n)
            acc[m][n] = __builtin_amdgcn_mfma_f32_32x32x16_bf16(
                af[m], bf[n], acc[m][n], 0, 0, 0);
      }
    }
    __builtin_amdgcn_s_barrier();  // buf[cur] reads done before overwrite

    if (gt == 5) {
      // g3^T: D[j][i]; sum over j (rows+regs+halves) -> rs3[i]
      flush_cheap(acc, sums + 6 * 4096, rowbase + wr * 128, lane);
    } else if (gt == 7) {
      flush_full(acc, sums, sums + 4096, rowbase + wr * 128,
                 colbase + wc * 64, lane);
    } else if (gt == 9) {
      flush_full(acc, sums + 2 * 4096, sums + 3 * 4096, rowbase + wr * 128,
                 colbase + wc * 64, lane);
    }
    buf ^= 1;
  }
  flush_full(acc, sums + 4 * 4096, sums + 5 * 4096, rowbase + wr * 128,
             colbase + wc * 64, lane);
#undef STAGE
#undef SCHED
}

// ---------------------------------------------------------------------------
// Final scalar reduction.
__global__ __launch_bounds__(1024) void loss_kernel(
    const float* __restrict__ sums, const float* __restrict__ dxyz,
    float* __restrict__ out) {
  const float* rs0 = sums;
  const float* cs0 = sums + 4096;
  const float* rs1 = sums + 2 * 4096;
  const float* cs1 = sums + 3 * 4096;
  const float* rs2 = sums + 4 * 4096;
  const float* cs2 = sums + 5 * 4096;
  const float* rs3 = sums + 6 * 4096;
  int tid = threadIdx.x;
  float acc = 0.0f;
  for (int i = tid; i < BHALF; i += 1024) {
    float dxv = dxyz[i];
    float dyv = dxyz[4096 + i];
    float dzv = dxyz[2 * 4096 + i];
    float lx = logf(rs0[i] + rs1[i]) - TEMP_INV * dxv;
    float ly = logf(cs0[i] + rs2[i]) - TEMP_INV * dyv;
    float lz = logf(cs1[i] + cs2[i]) - TEMP_INV * dzv;
    float lv = logf(rs3[i]) - TEMP_INV * (dxv + dyv + dzv);
    acc += lx + ly + lz + lv;
  }
  __shared__ float red[16];
#pragma unroll
  for (int m = 1; m < 64; m <<= 1) acc += __shfl_xor(acc, m, 64);
  if ((tid & 63) == 0) red[tid >> 6] = acc;
  __syncthreads();
  if (tid == 0) {
    float t = 0.0f;
#pragma unroll
    for (int i = 0; i < 16; ++i) t += red[i];
    out[0] = t * (1.0f / 4096.0f);
  }
}

// ---------------------------------------------------------------------------
extern "C" void kernel_launch(void* const* d_in, const int* in_sizes, int n_in,
                              void* d_out, int out_size, void* d_ws,
                              size_t ws_size, hipStream_t stream) {
  const float* x = (const float*)d_in[0];
  const float* y = (const float*)d_in[1];
  const float* z = (const float*)d_in[2];
  char* ws = (char*)d_ws;
  ushort* nrm1 = (ushort*)ws;                       // 4096*384 bf16
  ushort* nrm2 = nrm1 + (size_t)BHALF * KCAT;       // 4096*384 bf16
  float* sums = (float*)(ws + 2 * (size_t)BHALF * KCAT * sizeof(ushort));
  float* dxyz = sums + 7 * 4096;                    // 3*4096 fp32

  hipMemsetAsync(sums, 0, 7 * 4096 * sizeof(float), stream);
  norm_diag_kernel<<<3 * BHALF / 4, 256, 0, stream>>>(x, y, z, nrm1, nrm2,
                                                      dxyz);
  gram_fused_kernel<<<dim3(16, 16), 512, 0, stream>>>(nrm1, nrm2, sums);
  loss_kernel<<<1, 1024, 0, stream>>>(sums, dxyz, (float*)d_out);
}

// Round 7
// 83.944 us; speedup vs baseline: 5.7267x; 5.7267x over previous
//
#include <hip/hip_runtime.h>
#include <hip/hip_bf16.h>

// Problem constants
#define BHALF 4096      // B = 8192/2
#define DDIM 128        // feature dim per matrix
#define KCAT 384        // 3*DDIM, packed row width
#define TEMP_INV 10.0f  // 1/TEMP
#define EXP2K 14.426950408889634f  // 10 * log2(e): exp(v*10) = exp2(v*EXP2K)

typedef __attribute__((ext_vector_type(8))) short short8;   // 8 bf16
typedef __attribute__((ext_vector_type(4))) float f32x4;    // 16x16 MFMA acc

// Async global->LDS, 16B per lane. LDS dest is wave-uniform base (HW adds
// lane*16). Global source is per-lane.
__device__ __forceinline__ void gload16(const ushort* g, ushort* l) {
  __builtin_amdgcn_global_load_lds(
      (const __attribute__((address_space(1))) unsigned int*)g,
      (__attribute__((address_space(3))) unsigned int*)l, 16, 0, 0);
}

// ---------------------------------------------------------------------------
// Fused normalize + diag: one wave per (matrix, row-pair i).
__global__ __launch_bounds__(256) void norm_diag_kernel(
    const float* __restrict__ x, const float* __restrict__ y,
    const float* __restrict__ z, ushort* __restrict__ nrm1,
    ushort* __restrict__ nrm2, float* __restrict__ dxyz) {
  int wave = threadIdx.x >> 6;
  int lane = threadIdx.x & 63;
  int gi = blockIdx.x * 4 + wave;  // 0 .. 3*4096-1
  int mat = gi >> 12;
  int i = gi & 4095;
  const float* src = (mat == 0 ? x : (mat == 1 ? y : z));
  float2 a = *(const float2*)(src + (size_t)i * DDIM + lane * 2);
  float2 b = *(const float2*)(src + (size_t)(i + BHALF) * DDIM + lane * 2);
  float s1 = a.x * a.x + a.y * a.y;
  float s2 = b.x * b.x + b.y * b.y;
  float d = a.x * b.x + a.y * b.y;
#pragma unroll
  for (int m = 1; m < 64; m <<= 1) {
    s1 += __shfl_xor(s1, m, 64);
    s2 += __shfl_xor(s2, m, 64);
    d += __shfl_xor(d, m, 64);
  }
  float r1 = 1.0f / fmaxf(sqrtf(s1), 1e-12f);
  float r2 = 1.0f / fmaxf(sqrtf(s2), 1e-12f);
  ushort* d1 = nrm1 + (size_t)i * KCAT + mat * DDIM + lane * 2;
  ushort* d2 = nrm2 + (size_t)i * KCAT + mat * DDIM + lane * 2;
  __hip_bfloat162 o1, o2;
  o1.x = __float2bfloat16(a.x * r1);
  o1.y = __float2bfloat16(a.y * r1);
  o2.x = __float2bfloat16(b.x * r2);
  o2.y = __float2bfloat16(b.y * r2);
  *(__hip_bfloat162*)d1 = o1;
  *(__hip_bfloat162*)d2 = o2;
  if (lane == 0) dxyz[mat * BHALF + i] = d * r1 * r2;
}

// ---------------------------------------------------------------------------
// Flush helpers. 16x16 C/D layout (verified R1/R2): col = lane&15,
// row = (lane>>4)*4 + r.

// g3^T (operand-swapped mfma(b,a)): D[j][i]; the only needed reduction is
// over j = (D rows): regs + xor16 + xor32. dst[base + m*16 + (lane&15)].
__device__ __forceinline__ void flush_cheap(f32x4 (&acc)[4][4],
                                            float* __restrict__ dst, int base,
                                            int lane) {
#pragma unroll
  for (int m = 0; m < 4; ++m) {
    float s = 0.0f;
#pragma unroll
    for (int n = 0; n < 4; ++n)
#pragma unroll
      for (int r = 0; r < 4; ++r) s += exp2f(acc[m][n][r] * EXP2K);
    s += __shfl_xor(s, 16, 64);
    s += __shfl_xor(s, 32, 64);
    if (lane < 16) atomicAdd(&dst[base + m * 16 + lane], s);
#pragma unroll
    for (int n = 0; n < 4; ++n)
#pragma unroll
      for (int r = 0; r < 4; ++r) acc[m][n][r] = 0.0f;
  }
}

// Full flush: D[i][j]; rs[i] += sum_j exp, cs[j] += sum_i exp.
__device__ __forceinline__ void flush_full(f32x4 (&acc)[4][4],
                                           float* __restrict__ rs,
                                           float* __restrict__ cs, int rbase,
                                           int cbase, int lane) {
#pragma unroll
  for (int m = 0; m < 4; ++m)
#pragma unroll
    for (int n = 0; n < 4; ++n)
#pragma unroll
      for (int r = 0; r < 4; ++r)
        acc[m][n][r] = exp2f(acc[m][n][r] * EXP2K);

  // row sums: reduce over j (cols): n + xor over lane&15
#pragma unroll
  for (int m = 0; m < 4; ++m) {
    float rsum[4];
#pragma unroll
    for (int r = 0; r < 4; ++r)
      rsum[r] = acc[m][0][r] + acc[m][1][r] + acc[m][2][r] + acc[m][3][r];
#pragma unroll
    for (int r = 0; r < 4; ++r) {
      rsum[r] += __shfl_xor(rsum[r], 1, 64);
      rsum[r] += __shfl_xor(rsum[r], 2, 64);
      rsum[r] += __shfl_xor(rsum[r], 4, 64);
      rsum[r] += __shfl_xor(rsum[r], 8, 64);
    }
    if ((lane & 15) == 0) {
      int rb = rbase + m * 16 + (lane >> 4) * 4;
#pragma unroll
      for (int r = 0; r < 4; ++r) atomicAdd(&rs[rb + r], rsum[r]);
    }
  }

  // col sums: reduce over i (rows): m, r, xor16, xor32
#pragma unroll
  for (int n = 0; n < 4; ++n) {
    float csum = 0.0f;
#pragma unroll
    for (int m = 0; m < 4; ++m)
#pragma unroll
      for (int r = 0; r < 4; ++r) csum += acc[m][n][r];
    csum += __shfl_xor(csum, 16, 64);
    csum += __shfl_xor(csum, 32, 64);
    if (lane < 16) atomicAdd(&cs[cbase + n * 16 + lane], csum);
#pragma unroll
    for (int m = 0; m < 4; ++m)
#pragma unroll
      for (int r = 0; r < 4; ++r) acc[m][n][r] = 0.0f;
  }
}

// ---------------------------------------------------------------------------
// Fused 4-gram kernel v3: 256x128 tile, 8 waves (4 row-groups x 2
// col-groups, wave tile 64x64), 16x16x32 bf16 MFMA, acc[4][4] f32x4 = 64
// VGPR/thread (fits the observed 128-VGPR cap for 512-thr kernels; R5/R6's
// 128-float acc spilled 1.77 GB to scratch).
// LDS: [buf][kh][row][32] ushort, 64B rows (R2's measured-0-conflict
// geometry; 128B rows alias banks: row*32 % 32 == 0).
// 12 K-steps (BK=64 = 2 kh slabs): t0-5 g3^T = mfma(nrm2_frag, nrm1_frag)
// K=384; t6-7 g0 = x1·y1^T; t8-9 g1 = x1·z1^T; t10-11 g2 = y1·z1^T.
// Double-buffered, counted vmcnt(6) (6 loads/wave/step).
// sums layout (4096 floats each): [rs0, cs0, rs1, cs1, rs2, cs2, rs3]
__global__ __launch_bounds__(512)
__attribute__((amdgpu_waves_per_eu(2))) void gram_fused_kernel(
    const ushort* __restrict__ nrm1, const ushort* __restrict__ nrm2,
    float* __restrict__ sums) {
  __shared__ ushort As[2 * 2 * 256 * 32];  // 64 KB: buf*16384+kh*8192+row*32
  __shared__ ushort Bs[2 * 2 * 128 * 32];  // 32 KB: buf*8192+kh*4096+row*32

  int tid = threadIdx.x;
  int lane = tid & 63;
  int wave = tid >> 6;  // 0..7
  int wr = wave >> 1;   // 0..3: rows wr*64
  int wc = wave & 1;    // 0..1: cols wc*64

  int rowbase = blockIdx.x * 256;
  int colbase = blockIdx.y * 128;

  // Staging: lane l -> LDS row base+(l>>2), 16B chunk (l&3); source chunk
  // pre-swizzled by ((row mod 16)>>1)&3 = (l>>3)&3 (R2 involution).
  int srow = lane >> 2;
  int swz8 = ((lane & 3) ^ ((lane >> 3) & 3)) << 3;
  const ushort* gA =
      nrm1 + (size_t)(rowbase + wave * 32 + srow) * KCAT + swz8;
  const ushort* gB1 =
      nrm1 + (size_t)(colbase + wave * 16 + srow) * KCAT + swz8;
  const ushort* gB2 =
      nrm2 + (size_t)(colbase + wave * 16 + srow) * KCAT + swz8;

  // Fragment reads (R2): row = grp*16 + rsel, k-chunk fc = lane>>4,
  // slot = fc ^ ((rsel>>1)&3).
  int rsel = lane & 15;
  int slot8 = (((lane >> 4) ^ ((rsel >> 1) & 3)) << 3);

  f32x4 acc[4][4] = {};

#define SCHED(t, ao, bp)                                                    \
  do {                                                                      \
    if ((t) < 6)       { ao = (t) * 64;            bp = gB2 + (t) * 64; }   \
    else if ((t) < 8)  { ao = ((t)-6) * 64;        bp = gB1 + 128 + ((t)-6) * 64; } \
    else if ((t) < 10) { ao = ((t)-8) * 64;        bp = gB1 + 256 + ((t)-8) * 64; } \
    else               { ao = 128 + ((t)-10) * 64; bp = gB1 + 256 + ((t)-10) * 64; } \
  } while (0)

  // A: 4 loads (kh = ld>>1, row half = ld&1); B: 2 loads (kh = ld).
#define STAGE(b, ao, bp)                                                    \
  do {                                                                      \
    _Pragma("unroll") for (int ld = 0; ld < 4; ++ld)                        \
      gload16(gA + (ao) + (size_t)(ld & 1) * 16 * KCAT + (ld >> 1) * 32,    \
              &As[(b) * 16384 + (ld >> 1) * 8192 + wave * 1024 +            \
                  (ld & 1) * 512]);                                         \
    _Pragma("unroll") for (int ld = 0; ld < 2; ++ld)                        \
      gload16((bp) + ld * 32,                                               \
              &Bs[(b) * 8192 + ld * 4096 + wave * 512]);                    \
  } while (0)

  {
    int ao; const ushort* bp;
    SCHED(0, ao, bp);
    STAGE(0, ao, bp);
  }

  int buf = 0;
  for (int gt = 0; gt < 12; ++gt) {
    if (gt < 11) {
      int ao; const ushort* bp;
      SCHED(gt + 1, ao, bp);
      STAGE(buf ^ 1, ao, bp);
      // wait only for this step's 6 loads; next step's 6 stay in flight
      asm volatile("s_waitcnt vmcnt(6)" ::: "memory");
    } else {
      asm volatile("s_waitcnt vmcnt(0)" ::: "memory");
    }
    __builtin_amdgcn_s_barrier();
    __builtin_amdgcn_sched_barrier(0);  // no LDS-read hoisting above barrier

    const ushort* A = &As[buf * 16384];
    const ushort* B = &Bs[buf * 8192];
    bool g3 = (gt < 6);
#pragma unroll
    for (int kk = 0; kk < 2; ++kk) {
      short8 af[4], bf[4];
#pragma unroll
      for (int m = 0; m < 4; ++m)
        af[m] = *(const short8*)&A[kk * 8192 +
                                   (wr * 64 + m * 16 + rsel) * 32 + slot8];
#pragma unroll
      for (int n = 0; n < 4; ++n)
        bf[n] = *(const short8*)&B[kk * 4096 +
                                   (wc * 64 + n * 16 + rsel) * 32 + slot8];
      if (g3) {
#pragma unroll
        for (int m = 0; m < 4; ++m)
#pragma unroll
          for (int n = 0; n < 4; ++n)
            acc[m][n] = __builtin_amdgcn_mfma_f32_16x16x32_bf16(
                bf[n], af[m], acc[m][n], 0, 0, 0);
      } else {
#pragma unroll
        for (int m = 0; m < 4; ++m)
#pragma unroll
          for (int n = 0; n < 4; ++n)
            acc[m][n] = __builtin_amdgcn_mfma_f32_16x16x32_bf16(
                af[m], bf[n], acc[m][n], 0, 0, 0);
      }
    }
    __builtin_amdgcn_s_barrier();  // buf reads done before its next overwrite

    if (gt == 5) {
      flush_cheap(acc, sums + 6 * 4096, rowbase + wr * 64, lane);
    } else if (gt == 7) {
      flush_full(acc, sums, sums + 4096, rowbase + wr * 64,
                 colbase + wc * 64, lane);
    } else if (gt == 9) {
      flush_full(acc, sums + 2 * 4096, sums + 3 * 4096, rowbase + wr * 64,
                 colbase + wc * 64, lane);
    }
    buf ^= 1;
  }
  flush_full(acc, sums + 4 * 4096, sums + 5 * 4096, rowbase + wr * 64,
             colbase + wc * 64, lane);
#undef STAGE
#undef SCHED
}

// ---------------------------------------------------------------------------
// Final scalar reduction.
__global__ __launch_bounds__(1024) void loss_kernel(
    const float* __restrict__ sums, const float* __restrict__ dxyz,
    float* __restrict__ out) {
  const float* rs0 = sums;
  const float* cs0 = sums + 4096;
  const float* rs1 = sums + 2 * 4096;
  const float* cs1 = sums + 3 * 4096;
  const float* rs2 = sums + 4 * 4096;
  const float* cs2 = sums + 5 * 4096;
  const float* rs3 = sums + 6 * 4096;
  int tid = threadIdx.x;
  float acc = 0.0f;
  for (int i = tid; i < BHALF; i += 1024) {
    float dxv = dxyz[i];
    float dyv = dxyz[4096 + i];
    float dzv = dxyz[2 * 4096 + i];
    float lx = logf(rs0[i] + rs1[i]) - TEMP_INV * dxv;
    float ly = logf(cs0[i] + rs2[i]) - TEMP_INV * dyv;
    float lz = logf(cs1[i] + cs2[i]) - TEMP_INV * dzv;
    float lv = logf(rs3[i]) - TEMP_INV * (dxv + dyv + dzv);
    acc += lx + ly + lz + lv;
  }
  __shared__ float red[16];
#pragma unroll
  for (int m = 1; m < 64; m <<= 1) acc += __shfl_xor(acc, m, 64);
  if ((tid & 63) == 0) red[tid >> 6] = acc;
  __syncthreads();
  if (tid == 0) {
    float t = 0.0f;
#pragma unroll
    for (int i = 0; i < 16; ++i) t += red[i];
    out[0] = t * (1.0f / 4096.0f);
  }
}

// ---------------------------------------------------------------------------
extern "C" void kernel_launch(void* const* d_in, const int* in_sizes, int n_in,
                              void* d_out, int out_size, void* d_ws,
                              size_t ws_size, hipStream_t stream) {
  const float* x = (const float*)d_in[0];
  const float* y = (const float*)d_in[1];
  const float* z = (const float*)d_in[2];
  char* ws = (char*)d_ws;
  ushort* nrm1 = (ushort*)ws;                       // 4096*384 bf16
  ushort* nrm2 = nrm1 + (size_t)BHALF * KCAT;       // 4096*384 bf16
  float* sums = (float*)(ws + 2 * (size_t)BHALF * KCAT * sizeof(ushort));
  float* dxyz = sums + 7 * 4096;                    // 3*4096 fp32

  hipMemsetAsync(sums, 0, 7 * 4096 * sizeof(float), stream);
  norm_diag_kernel<<<3 * BHALF / 4, 256, 0, stream>>>(x, y, z, nrm1, nrm2,
                                                      dxyz);
  gram_fused_kernel<<<dim3(16, 32), 512, 0, stream>>>(nrm1, nrm2, sums);
  loss_kernel<<<1, 1024, 0, stream>>>(sums, dxyz, (float*)d_out);
}